// Round 1
// baseline (210.963 us; speedup 1.0000x reference)
//
#include <hip/hip_runtime.h>
#include <stdint.h>

#define Bn  8
#define LQn 2048
#define LKn 2048
#define Dn  512

using f32x4  = __attribute__((ext_vector_type(4))) float;
using bf16x8 = __attribute__((ext_vector_type(8))) __bf16;
using u16x4  = __attribute__((ext_vector_type(4))) unsigned short;
using u16x8  = __attribute__((ext_vector_type(8))) unsigned short;

#define WS_FLAG_OFF 0
#define WS_MASK_OFF 256
#define WS_K_OFF    (WS_MASK_OFF + Bn*LKn*4)
#define WS_VT_OFF   (WS_K_OFF + Bn*LKn*Dn*2)
#define WS_REQ      ((size_t)WS_VT_OFF + (size_t)Bn*LKn*Dn*2)

union BFU { __bf16 h; unsigned short u; };
static __device__ __forceinline__ unsigned short f2bfu(float x) { BFU t; t.h = (__bf16)x; return t.u; }

static __device__ __forceinline__ void gload16(const void* g, void* l) {
  __builtin_amdgcn_global_load_lds((const __attribute__((address_space(1))) void*)g,
                                   (__attribute__((address_space(3))) void*)l,
                                   16, 0, 0);
}

// ---- mask dtype detection: 0=int32, 1=uint8/bool, 2=float32 ----
__global__ void detect_mask_kernel(const unsigned char* __restrict__ m, int* __restrict__ flag) {
  __shared__ int sBig, sOff;
  if (threadIdx.x == 0) { sBig = 0; sOff = 0; }
  __syncthreads();
  int big = 0, off = 0;
  for (int i = threadIdx.x; i < Bn*LKn; i += blockDim.x) {
    unsigned char v = m[i];
    big |= (v > 1) ? 1 : 0;
    off |= (((i & 3) != 0) && v != 0) ? 1 : 0;
  }
  if (big) atomicOr(&sBig, 1);
  if (off) atomicOr(&sOff, 1);
  __syncthreads();
  if (threadIdx.x == 0) *flag = sBig ? 2 : (sOff ? 1 : 0);
}

__global__ void build_mask_kernel(const void* __restrict__ mraw, const int* __restrict__ flag,
                                  float* __restrict__ maskadd) {
  int i = blockIdx.x * blockDim.x + threadIdx.x;
  if (i >= Bn*LKn) return;
  int f = *flag;
  bool masked;
  if (f == 2)      masked = ((const float*)mraw)[i] != 0.0f;
  else if (f == 1) masked = ((const unsigned char*)mraw)[i] != 0;
  else             masked = ((const int*)mraw)[i] != 0;
  maskadd[i] = masked ? -1e30f : 0.0f;
}

// ---- K fp32 -> bf16 (same layout) ----
__global__ void conv_k_kernel(const float* __restrict__ src, unsigned short* __restrict__ dst) {
  int i = blockIdx.x * blockDim.x + threadIdx.x;  // one thread per 8 elements
  const f32x4* s4 = (const f32x4*)src + (size_t)i * 2;
  f32x4 a = s4[0], b = s4[1];
  u16x8 o;
#pragma unroll
  for (int j = 0; j < 4; ++j) { o[j] = f2bfu(a[j]); o[j+4] = f2bfu(b[j]); }
  *((u16x8*)dst + i) = o;
}

// ---- V fp32 [B][LK][D] -> Vt bf16 [B][D][LK] ----
__global__ void conv_vt_kernel(const float* __restrict__ v, unsigned short* __restrict__ vt) {
  __shared__ float t[64][65];
  const int b = blockIdx.z, dt = blockIdx.y, kt = blockIdx.x;
  const float* vbase = v + ((size_t)(b*LKn) + kt*64)*Dn + dt*64;
  for (int i = threadIdx.x; i < 64*64; i += blockDim.x) {
    int kk = i >> 6, dd = i & 63;
    t[kk][dd] = vbase[(size_t)kk*Dn + dd];
  }
  __syncthreads();
  unsigned short* vtbase = vt + ((size_t)(b*Dn) + dt*64)*LKn + kt*64;
  for (int i = threadIdx.x; i < 64*16; i += blockDim.x) {
    int dd = i >> 4, kg = (i & 15) * 4;
    u16x4 o;
#pragma unroll
    for (int j = 0; j < 4; ++j) o[j] = f2bfu(t[kg+j][dd]);
    *(u16x4*)(vtbase + (size_t)dd*LKn + kg) = o;
  }
}

// ---- flash attention: QBLK=64, KVBLK=64, 8 waves ----
__launch_bounds__(512, 2)
__global__ void attn_kernel(const float* __restrict__ q, const unsigned short* __restrict__ kb,
                            const unsigned short* __restrict__ vtb,
                            const float* __restrict__ ratio, const float* __restrict__ scalep,
                            const float* __restrict__ maskadd, float* __restrict__ out) {
  __shared__ __align__(16) unsigned short Klds[64*512];   // 64 KiB  [key][d] swz slot^=(key&7)
  __shared__ __align__(16) unsigned short Vtlds[512*64];  // 64 KiB  [d][key] swz slot^=(d&7)
  __shared__ __align__(16) unsigned short Plds[64*64];    // 8 KiB   [q][key] swz slot^=(q&7)
  __shared__ float redm[2][64];
  __shared__ float reds[2][64];

  const int tid = threadIdx.x;
  const int w = tid >> 6, lane = tid & 63;
  const int lane16 = lane & 15, lgrp = lane >> 4;
  const int qf = w & 3, dhalf = w >> 2;
  const int bid = blockIdx.x;
  const int b = bid & 7, qtile = bid >> 3;   // XCD-affine: each XCD owns one batch
  const int qbase = qtile * 64;

  const float c = scalep[0] * ratio[b];

  // Hoist Q fragments: A-frag row = lane16, k = lgrp*8 + j
  bf16x8 qfrag[16];
  {
    const float* qrow = q + ((size_t)(b*LQn) + qbase + qf*16 + lane16) * Dn;
#pragma unroll
    for (int ks = 0; ks < 16; ++ks) {
      const int d0 = ks*32 + lgrp*8;
      f32x4 a = *(const f32x4*)(qrow + d0);
      f32x4 bb = *(const f32x4*)(qrow + d0 + 4);
      bf16x8 f;
#pragma unroll
      for (int j = 0; j < 4; ++j) { f[j] = (__bf16)a[j]; f[j+4] = (__bf16)bb[j]; }
      qfrag[ks] = f;
    }
  }

  f32x4 o[16];
#pragma unroll
  for (int i = 0; i < 16; ++i) { o[i][0]=0.f; o[i][1]=0.f; o[i][2]=0.f; o[i][3]=0.f; }
  float mrow[4], lrow[4];
#pragma unroll
  for (int r = 0; r < 4; ++r) { mrow[r] = -3e38f; lrow[r] = 0.f; }

  const char* kgbase  = (const char*)kb  + (size_t)b*LKn*Dn*2;
  const char* vtgbase = (const char*)vtb + (size_t)b*Dn*LKn*2;
  const float* madd = maskadd + b*LKn;

  const int key0 = dhalf*32 + lane16;   // within-tile key col of frag 0
  const int key1 = key0 + 16;

  for (int t = 0; t < LKn/64; ++t) {
    const int kbase = t*64;
    // stage K tile: wave w, iter j -> LDS row k=j*8+w (linear dest), source pre-swizzled
#pragma unroll
    for (int j = 0; j < 8; ++j) {
      const int k = j*8 + w;
      gload16(kgbase + ((size_t)(kbase + k))*1024 + ((lane ^ w) * 16),
              (char*)Klds + (size_t)k*1024);
    }
    // stage Vt tile: dest = j*8192 + w*1024 + lane*16 -> d = j*64+w*8+(lane>>3), slot = lane&7
#pragma unroll
    for (int j = 0; j < 8; ++j) {
      const int drow = j*64 + w*8 + (lane >> 3);
      const int srcslot = (lane & 7) ^ (lane >> 3);
      gload16(vtgbase + (size_t)drow*4096 + (size_t)kbase*2 + srcslot*16,
              (char*)Vtlds + j*8192 + w*1024);
    }
    __syncthreads();

    // QK^T: S[16q x 32key] per wave as two 16x16 frags
    f32x4 s0, s1;
    s0[0]=s0[1]=s0[2]=s0[3]=0.f; s1[0]=s1[1]=s1[2]=s1[3]=0.f;
#pragma unroll
    for (int ks = 0; ks < 16; ++ks) {
      const int slot = ks*4 + lgrp;
      const bf16x8 b0 = *(const bf16x8*)((const char*)Klds + (size_t)key0*1024 + ((slot ^ (key0 & 7)) * 16));
      const bf16x8 b1 = *(const bf16x8*)((const char*)Klds + (size_t)key1*1024 + ((slot ^ (key1 & 7)) * 16));
      s0 = __builtin_amdgcn_mfma_f32_16x16x32_bf16(qfrag[ks], b0, s0, 0, 0, 0);
      s1 = __builtin_amdgcn_mfma_f32_16x16x32_bf16(qfrag[ks], b1, s1, 0, 0, 0);
    }

    // scale + additive mask
    const float m0 = madd[kbase + key0];
    const float m1 = madd[kbase + key1];
#pragma unroll
    for (int r = 0; r < 4; ++r) { s0[r] = s0[r]*c + m0; s1[r] = s1[r]*c + m1; }

    // per-row max: row = qf*16 + lgrp*4 + r lives in the 16-lane group
    float tmax[4];
#pragma unroll
    for (int r = 0; r < 4; ++r) {
      float vv = fmaxf(s0[r], s1[r]);
      vv = fmaxf(vv, __shfl_xor(vv, 1));
      vv = fmaxf(vv, __shfl_xor(vv, 2));
      vv = fmaxf(vv, __shfl_xor(vv, 4));
      vv = fmaxf(vv, __shfl_xor(vv, 8));
      tmax[r] = vv;
    }
    if (lane16 == 0) {
#pragma unroll
      for (int r = 0; r < 4; ++r) redm[dhalf][qf*16 + lgrp*4 + r] = tmax[r];
    }
    __syncthreads();

    float mnew[4], fac[4];
#pragma unroll
    for (int r = 0; r < 4; ++r) {
      const int row = qf*16 + lgrp*4 + r;
      const float mt = fmaxf(redm[0][row], redm[1][row]);
      mnew[r] = fmaxf(mrow[r], mt);
      fac[r] = exp2f((mrow[r] - mnew[r]) * 1.4426950408889634f);
    }

    float psum[4];
#pragma unroll
    for (int r = 0; r < 4; ++r) {
      s0[r] = exp2f((s0[r] - mnew[r]) * 1.4426950408889634f);
      s1[r] = exp2f((s1[r] - mnew[r]) * 1.4426950408889634f);
      float vv = s0[r] + s1[r];
      vv += __shfl_xor(vv, 1);
      vv += __shfl_xor(vv, 2);
      vv += __shfl_xor(vv, 4);
      vv += __shfl_xor(vv, 8);
      psum[r] = vv;
    }
    if (lane16 == 0) {
#pragma unroll
      for (int r = 0; r < 4; ++r) reds[dhalf][qf*16 + lgrp*4 + r] = psum[r];
    }
    // write P tile (bf16, swizzled)
#pragma unroll
    for (int r = 0; r < 4; ++r) {
      const int prow = qf*16 + lgrp*4 + r;
      char* pb = (char*)Plds + prow*128;
      *(unsigned short*)(pb + (((key0 >> 3) ^ (prow & 7)) * 16) + (key0 & 7)*2) = f2bfu(s0[r]);
      *(unsigned short*)(pb + (((key1 >> 3) ^ (prow & 7)) * 16) + (key1 & 7)*2) = f2bfu(s1[r]);
    }
    __syncthreads();

    // online-softmax state update + O rescale
#pragma unroll
    for (int r = 0; r < 4; ++r) {
      const int row = qf*16 + lgrp*4 + r;
      lrow[r] = lrow[r]*fac[r] + (reds[0][row] + reds[1][row]);
      mrow[r] = mnew[r];
    }
#pragma unroll
    for (int i = 0; i < 16; ++i) {
#pragma unroll
      for (int r = 0; r < 4; ++r) o[i][r] *= fac[r];
    }

    // PV: O[16q x 256d per wave] += P(16x64) @ V(64x256)
#pragma unroll
    for (int ks2 = 0; ks2 < 2; ++ks2) {
      const int prow = qf*16 + lane16;
      const int slot = ks2*4 + lgrp;
      const bf16x8 pa = *(const bf16x8*)((const char*)Plds + prow*128 + ((slot ^ (prow & 7)) * 16));
#pragma unroll
      for (int df = 0; df < 16; ++df) {
        const int drow = dhalf*256 + df*16 + lane16;
        const bf16x8 vb = *(const bf16x8*)((const char*)Vtlds + drow*128 + ((slot ^ (drow & 7)) * 16));
        o[df] = __builtin_amdgcn_mfma_f32_16x16x32_bf16(pa, vb, o[df], 0, 0, 0);
      }
    }
    __syncthreads();
  }

  // epilogue: out = O / l
#pragma unroll
  for (int df = 0; df < 16; ++df) {
    const int d = dhalf*256 + df*16 + lane16;
#pragma unroll
    for (int r = 0; r < 4; ++r) {
      const int qrow = qbase + qf*16 + lgrp*4 + r;
      out[((size_t)(b*LQn) + qrow)*Dn + d] = o[df][r] / lrow[r];
    }
  }
}

extern "C" void kernel_launch(void* const* d_in, const int* in_sizes, int n_in,
                              void* d_out, int out_size, void* d_ws, size_t ws_size,
                              hipStream_t stream) {
  const float* q      = (const float*)d_in[0];
  const float* k      = (const float*)d_in[1];
  const float* v      = (const float*)d_in[2];
  const float* ratio  = (const float*)d_in[3];
  const float* scalep = (const float*)d_in[4];
  const void*  mask   = d_in[5];
  float* out = (float*)d_out;
  char* ws = (char*)d_ws;

  if (ws_size < WS_REQ) return;  // insufficient scratch: fail loudly (validation catches it)

  int*   flag    = (int*)(ws + WS_FLAG_OFF);
  float* maskadd = (float*)(ws + WS_MASK_OFF);
  unsigned short* kbf = (unsigned short*)(ws + WS_K_OFF);
  unsigned short* vtb = (unsigned short*)(ws + WS_VT_OFF);

  hipLaunchKernelGGL(detect_mask_kernel, dim3(1), dim3(256), 0, stream,
                     (const unsigned char*)mask, flag);
  hipLaunchKernelGGL(build_mask_kernel, dim3((Bn*LKn + 255)/256), dim3(256), 0, stream,
                     mask, flag, maskadd);
  hipLaunchKernelGGL(conv_k_kernel, dim3(Bn*LKn*Dn/8/256), dim3(256), 0, stream, k, kbf);
  hipLaunchKernelGGL(conv_vt_kernel, dim3(LKn/64, Dn/64, Bn), dim3(256), 0, stream, v, vtb);
  hipLaunchKernelGGL(attn_kernel, dim3(Bn*(LQn/64)), dim3(512), 0, stream,
                     q, kbf, vtb, ratio, scalep, maskadd, out);
}